// Round 2
// baseline (631.177 us; speedup 1.0000x reference)
//
#include <hip/hip_runtime.h>
#include <math.h>

constexpr int Tn  = 512;
constexpr int Dn  = 512;   // DIM
constexpr int NH  = 8;
constexpr int DHn = 64;
constexpr float EPSR = 1.1920929e-07f;

// ---------------------------------------------------------------------------
// K1: pre RMSNorm + the three sigmoid gates (lr, decay, omega)
// grid = T blocks, 256 threads
// ---------------------------------------------------------------------------
__global__ __launch_bounds__(256) void k_norm_gates(
    const float* __restrict__ x, const float* __restrict__ pw,
    const float* __restrict__ lrw, const float* __restrict__ lrb,
    const float* __restrict__ dw,  const float* __restrict__ db,
    const float* __restrict__ gw,  const float* __restrict__ gb,
    float* __restrict__ xn, float* __restrict__ wgt, float* __restrict__ dec)
{
  const int t = blockIdx.x;
  const int tid = threadIdx.x;
  const int lane = tid & 63, wid = tid >> 6;
  __shared__ float xrow[Dn];
  __shared__ float red[4];
  __shared__ float gl[24];

  float v0 = x[t*Dn + tid];
  float v1 = x[t*Dn + 256 + tid];
  float ss = v0*v0 + v1*v1;
  #pragma unroll
  for (int o = 1; o < 64; o <<= 1) ss += __shfl_xor(ss, o, 64);
  if (lane == 0) red[wid] = ss;
  __syncthreads();
  float ms = (red[0] + red[1] + red[2] + red[3]) * (1.0f / Dn);
  float sc = rsqrtf(ms + EPSR);
  float xn0 = v0 * sc * pw[tid];
  float xn1 = v1 * sc * pw[tid + 256];
  xrow[tid] = xn0; xrow[tid + 256] = xn1;
  xn[t*Dn + tid] = xn0; xn[t*Dn + 256 + tid] = xn1;
  __syncthreads();

  // 24 dot products of length 512: gate g: 0..7=lr, 8..15=decay, 16..23=omega
  for (int g = wid; g < 24; g += 4) {
    const float* W = (g < 8) ? lrw : (g < 16) ? dw : gw;
    const int hh = g & 7;
    float acc = 0.f;
    #pragma unroll
    for (int j = 0; j < 8; ++j)
      acc += xrow[lane + j*64] * W[hh*Dn + lane + j*64];
    #pragma unroll
    for (int o = 1; o < 64; o <<= 1) acc += __shfl_xor(acc, o, 64);
    if (lane == 0) {
      float bias = ((g < 8) ? lrb : (g < 16) ? db : gb)[hh];
      gl[g] = 1.f / (1.f + __expf(-(acc + bias)));
    }
  }
  __syncthreads();
  if (tid < 8)        wgt[tid*Tn + t] = gl[16 + tid] * gl[tid];  // omega * lr
  else if (tid < 16)  dec[(tid - 8)*Tn + t] = gl[tid];           // decay
}

// ---------------------------------------------------------------------------
// K2: depthwise conv1d (K=4, pad 2 left / 1 effective right after trim)
// grid = T blocks, 512 threads (c = tid)
// ---------------------------------------------------------------------------
__global__ __launch_bounds__(512) void k_conv(
    const float* __restrict__ xn,
    const float* __restrict__ qcw, const float* __restrict__ kcw,
    const float* __restrict__ vcw,
    float* __restrict__ qin, float* __restrict__ kin, float* __restrict__ vin)
{
  const int t = blockIdx.x, c = threadIdx.x;
  float4 wq = *(const float4*)&qcw[c*4];
  float4 wk = *(const float4*)&kcw[c*4];
  float4 wv = *(const float4*)&vcw[c*4];
  float wqa[4] = {wq.x, wq.y, wq.z, wq.w};
  float wka[4] = {wk.x, wk.y, wk.z, wk.w};
  float wva[4] = {wv.x, wv.y, wv.z, wv.w};
  float aq = 0.f, ak = 0.f, av = 0.f;
  #pragma unroll
  for (int j = 0; j < 4; ++j) {
    int tt = t - 2 + j;
    if (tt >= 0 && tt < Tn) {
      float xv = xn[tt*Dn + c];
      aq = fmaf(xv, wqa[j], aq);
      ak = fmaf(xv, wka[j], ak);
      av = fmaf(xv, wva[j], av);
    }
  }
  qin[t*Dn + c] = aq;
  kin[t*Dn + c] = ak;
  vin[t*Dn + c] = av;
}

// ---------------------------------------------------------------------------
// K3: fp32 NT GEMM  C[m,n] = sum_k A[m,k] * B[n,k]   (M=N=K=512)
// grid (8,8,nz), 256 threads, 64x64 tile, BK=16, 4x4 micro-tile
// z selects (A + z*sA, B_z, C + z*sC)
// ---------------------------------------------------------------------------
__global__ __launch_bounds__(256) void k_gemm_nt(
    const float* __restrict__ Abase, long sA,
    const float* __restrict__ B0, const float* __restrict__ B1,
    const float* __restrict__ B2,
    float* __restrict__ Cbase, long sC)
{
  const int z = blockIdx.z;
  const float* A = Abase + (long)z * sA;
  const float* B = (z == 0) ? B0 : (z == 1) ? B1 : B2;
  float* C = Cbase + (long)z * sC;
  __shared__ float As[16][65];
  __shared__ float Bs[16][65];
  const int tid = threadIdx.x;
  const int m0 = blockIdx.x * 64, n0 = blockIdx.y * 64;
  const int lr_ = tid >> 2;          // 0..63 row within tile
  const int lc_ = (tid & 3) << 2;    // k-chunk 0,4,8,12
  const int ty = tid >> 4, tx = tid & 15;
  float acc[4][4] = {{0.f}};
  for (int k0 = 0; k0 < 512; k0 += 16) {
    float4 avv = *(const float4*)&A[(m0 + lr_)*512 + k0 + lc_];
    float4 bvv = *(const float4*)&B[(n0 + lr_)*512 + k0 + lc_];
    As[lc_+0][lr_] = avv.x; As[lc_+1][lr_] = avv.y;
    As[lc_+2][lr_] = avv.z; As[lc_+3][lr_] = avv.w;
    Bs[lc_+0][lr_] = bvv.x; Bs[lc_+1][lr_] = bvv.y;
    Bs[lc_+2][lr_] = bvv.z; Bs[lc_+3][lr_] = bvv.w;
    __syncthreads();
    #pragma unroll
    for (int k = 0; k < 16; ++k) {
      float a[4], b[4];
      #pragma unroll
      for (int i = 0; i < 4; ++i) a[i] = As[k][ty*4 + i];
      #pragma unroll
      for (int j = 0; j < 4; ++j) b[j] = Bs[k][tx*4 + j];
      #pragma unroll
      for (int i = 0; i < 4; ++i)
        #pragma unroll
        for (int j = 0; j < 4; ++j) acc[i][j] = fmaf(a[i], b[j], acc[i][j]);
    }
    __syncthreads();
  }
  #pragma unroll
  for (int i = 0; i < 4; ++i)
    #pragma unroll
    for (int j = 0; j < 4; ++j)
      C[(m0 + ty*4 + i)*512 + (n0 + tx*4 + j)] = acc[i][j];
}

// ---------------------------------------------------------------------------
// K4: per-head RMS norm of Q and K (in place), rms = ||x||/8 clamped 1e-8
// grid (NH, T, 2), 64 threads
// ---------------------------------------------------------------------------
__global__ __launch_bounds__(64) void k_mhrms(
    float* __restrict__ Qb, float* __restrict__ Kb,
    const float* __restrict__ qg, const float* __restrict__ kg)
{
  const int h = blockIdx.x, t = blockIdx.y, z = blockIdx.z, d = threadIdx.x;
  float* base = z ? Kb : Qb;
  const float* gm = z ? kg : qg;
  const int idx = t*Dn + h*DHn + d;
  float v = base[idx];
  float ss = v * v;
  #pragma unroll
  for (int o = 1; o < 64; o <<= 1) ss += __shfl_xor(ss, o, 64);
  float rms = sqrtf(ss) * 0.125f;
  base[idx] = v / fmaxf(rms, 1e-8f) * gm[h*DHn + d];
}

// ---------------------------------------------------------------------------
// K5: sequential affine recurrence, row-parallel.
// S_t = dec*(S_{t-1} - S_{t-1} G_t) + C_t ; G_t,C_t rank-8 (window sums).
// Row m of S evolves independently:
//   r <- dec*r + sum_s w_s (v_s[m] - dec*(r . k_s)) k_s
//   y_t[m] = r . q_t
// grid = NH*64 blocks (h,m), 64 threads (lane d owns r[d]).
// ---------------------------------------------------------------------------
__global__ __launch_bounds__(64) void k_rec(
    const float* __restrict__ Qn, const float* __restrict__ Kn,
    const float* __restrict__ V,
    const float* __restrict__ wgt, const float* __restrict__ dec,
    const float* __restrict__ S0, float* __restrict__ Y)
{
  const int h = blockIdx.x >> 6, m = blockIdx.x & 63, d = threadIdx.x;
  float r = S0[(h*DHn + m)*DHn + d];
  float kw[8], vw[8], ww[8];
  #pragma unroll
  for (int s = 0; s < 8; ++s) { kw[s] = 0.f; vw[s] = 0.f; ww[s] = 0.f; }
  const int cq = h*DHn + d;   // column for k/q loads (lane-indexed)
  const int cv = h*DHn + m;   // column for v loads / y stores (row-indexed)

  for (int tb = 0; tb < Tn/8; ++tb) {
    #pragma unroll
    for (int s8 = 0; s8 < 8; ++s8) {
      const int t = tb*8 + s8;
      float kn  = Kn[t*Dn + cq];
      float qd  = Qn[t*Dn + cq];
      float vn  = V [t*Dn + cv];          // lane-uniform
      float w_t = wgt[h*Tn + t];          // uniform
      float dc  = dec[h*Tn + t];          // uniform
      kw[s8] = kn; vw[s8] = vn; ww[s8] = w_t;   // static ring slot (unrolled)

      // 8 dot products u_s = r . k_s, batched butterfly reduction
      float p[8];
      #pragma unroll
      for (int s = 0; s < 8; ++s) p[s] = r * kw[s];
      #pragma unroll
      for (int o = 1; o <= 4; o <<= 1) {
        #pragma unroll
        for (int s = 0; s < 8; ++s) p[s] += __shfl_xor(p[s], o, 64);
      }
      // each 8-lane group now has all 8 partial sums; lane keeps p[lane&7]
      const int g = d & 7;
      float a0 = (g & 1) ? p[1] : p[0];
      float a1 = (g & 1) ? p[3] : p[2];
      float a2 = (g & 1) ? p[5] : p[4];
      float a3 = (g & 1) ? p[7] : p[6];
      float b0v = (g & 2) ? a1 : a0;
      float b1v = (g & 2) ? a3 : a2;
      float psel = (g & 4) ? b1v : b0v;
      #pragma unroll
      for (int o = 8; o <= 32; o <<= 1) psel += __shfl_xor(psel, o, 64);
      // lane s (s<8) now holds the full u_s; broadcast all 8
      float u[8];
      #pragma unroll
      for (int s = 0; s < 8; ++s) u[s] = __shfl(psel, s, 64);

      float bc[8];
      #pragma unroll
      for (int s = 0; s < 8; ++s) bc[s] = ww[s] * (vw[s] - dc * u[s]);
      r = dc * r;
      #pragma unroll
      for (int s = 0; s < 8; ++s) r = fmaf(bc[s], kw[s], r);

      // y_t[m] = r . q_t
      float py = r * qd;
      #pragma unroll
      for (int o = 1; o < 64; o <<= 1) py += __shfl_xor(py, o, 64);
      if (d == 0) Y[t*Dn + cv] = py;
    }
  }
}

// ---------------------------------------------------------------------------
extern "C" void kernel_launch(void* const* d_in, const int* in_sizes, int n_in,
                              void* d_out, int out_size, void* d_ws, size_t ws_size,
                              hipStream_t stream)
{
  const float* x   = (const float*)d_in[0];
  const float* pw  = (const float*)d_in[1];
  const float* Wq  = (const float*)d_in[2];
  const float* Wk  = (const float*)d_in[3];
  const float* Wv  = (const float*)d_in[4];
  const float* Wo  = (const float*)d_in[5];
  const float* qcw = (const float*)d_in[6];
  const float* kcw = (const float*)d_in[7];
  const float* vcw = (const float*)d_in[8];
  const float* lrw = (const float*)d_in[9];
  const float* lrb = (const float*)d_in[10];
  const float* dw  = (const float*)d_in[11];
  const float* db  = (const float*)d_in[12];
  const float* gw  = (const float*)d_in[13];
  const float* gb  = (const float*)d_in[14];
  const float* qg  = (const float*)d_in[15];
  const float* kg  = (const float*)d_in[16];
  const float* S0  = (const float*)d_in[17];
  float* out = (float*)d_out;
  float* ws  = (float*)d_ws;

  const long N = (long)Tn * Dn;   // 262144
  float* xn  = ws;
  float* qin = ws + 1*N;
  float* kin = ws + 2*N;
  float* vin = ws + 3*N;
  float* Qb  = ws + 4*N;
  float* Kb  = ws + 5*N;
  float* Vb  = ws + 6*N;
  float* Yb  = ws + 7*N;
  float* wgt = ws + 8*N;          // [NH][T]
  float* dcb = wgt + NH*Tn;       // [NH][T]

  k_norm_gates<<<Tn, 256, 0, stream>>>(x, pw, lrw, lrb, dw, db, gw, gb,
                                       xn, wgt, dcb);
  k_conv<<<Tn, Dn, 0, stream>>>(xn, qcw, kcw, vcw, qin, kin, vin);
  k_gemm_nt<<<dim3(8, 8, 3), 256, 0, stream>>>(qin, N, Wq, Wk, Wv, Qb, N);
  k_mhrms<<<dim3(NH, Tn, 2), 64, 0, stream>>>(Qb, Kb, qg, kg);
  k_rec<<<NH * DHn, 64, 0, stream>>>(Qb, Kb, Vb, wgt, dcb, S0, Yb);
  k_gemm_nt<<<dim3(8, 8, 1), 256, 0, stream>>>(Yb, 0, Wo, Wo, Wo, out, 0);
}

// Round 3
// 302.195 us; speedup vs baseline: 2.0886x; 2.0886x over previous
//
#include <hip/hip_runtime.h>
#include <math.h>

constexpr int Tn  = 512;
constexpr int Dn  = 512;   // DIM
constexpr int NH  = 8;
constexpr int DHn = 64;
constexpr int CL  = 16;    // chunk length
constexpr int NC  = Tn / CL; // 32 chunks
constexpr float EPSR = 1.1920929e-07f;

static __device__ __forceinline__ float rdlane(float v, int l) {
  return __uint_as_float((unsigned)__builtin_amdgcn_readlane((int)__float_as_uint(v), l));
}

// ---------------------------------------------------------------------------
// K1: pre RMSNorm + the three sigmoid gates (lr, decay, omega)
// ---------------------------------------------------------------------------
__global__ __launch_bounds__(256) void k_norm_gates(
    const float* __restrict__ x, const float* __restrict__ pw,
    const float* __restrict__ lrw, const float* __restrict__ lrb,
    const float* __restrict__ dw,  const float* __restrict__ db,
    const float* __restrict__ gw,  const float* __restrict__ gb,
    float* __restrict__ xn, float* __restrict__ wgt, float* __restrict__ dec)
{
  const int t = blockIdx.x;
  const int tid = threadIdx.x;
  const int lane = tid & 63, wid = tid >> 6;
  __shared__ float xrow[Dn];
  __shared__ float red[4];
  __shared__ float gl[24];

  float v0 = x[t*Dn + tid];
  float v1 = x[t*Dn + 256 + tid];
  float ss = v0*v0 + v1*v1;
  #pragma unroll
  for (int o = 1; o < 64; o <<= 1) ss += __shfl_xor(ss, o, 64);
  if (lane == 0) red[wid] = ss;
  __syncthreads();
  float ms = (red[0] + red[1] + red[2] + red[3]) * (1.0f / Dn);
  float sc = rsqrtf(ms + EPSR);
  float xn0 = v0 * sc * pw[tid];
  float xn1 = v1 * sc * pw[tid + 256];
  xrow[tid] = xn0; xrow[tid + 256] = xn1;
  xn[t*Dn + tid] = xn0; xn[t*Dn + 256 + tid] = xn1;
  __syncthreads();

  for (int g = wid; g < 24; g += 4) {
    const float* W = (g < 8) ? lrw : (g < 16) ? dw : gw;
    const int hh = g & 7;
    float acc = 0.f;
    #pragma unroll
    for (int j = 0; j < 8; ++j)
      acc += xrow[lane + j*64] * W[hh*Dn + lane + j*64];
    #pragma unroll
    for (int o = 1; o < 64; o <<= 1) acc += __shfl_xor(acc, o, 64);
    if (lane == 0) {
      float bias = ((g < 8) ? lrb : (g < 16) ? db : gb)[hh];
      gl[g] = 1.f / (1.f + __expf(-(acc + bias)));
    }
  }
  __syncthreads();
  if (tid < 8)        wgt[tid*Tn + t] = gl[16 + tid] * gl[tid];  // omega * lr
  else if (tid < 16)  dec[(tid - 8)*Tn + t] = gl[tid];           // decay
}

// ---------------------------------------------------------------------------
// K2: depthwise conv1d (K=4)
// ---------------------------------------------------------------------------
__global__ __launch_bounds__(512) void k_conv(
    const float* __restrict__ xn,
    const float* __restrict__ qcw, const float* __restrict__ kcw,
    const float* __restrict__ vcw,
    float* __restrict__ qin, float* __restrict__ kin, float* __restrict__ vin)
{
  const int t = blockIdx.x, c = threadIdx.x;
  float4 wq = *(const float4*)&qcw[c*4];
  float4 wk = *(const float4*)&kcw[c*4];
  float4 wv = *(const float4*)&vcw[c*4];
  float wqa[4] = {wq.x, wq.y, wq.z, wq.w};
  float wka[4] = {wk.x, wk.y, wk.z, wk.w};
  float wva[4] = {wv.x, wv.y, wv.z, wv.w};
  float aq = 0.f, ak = 0.f, av = 0.f;
  #pragma unroll
  for (int j = 0; j < 4; ++j) {
    int tt = t - 2 + j;
    if (tt >= 0 && tt < Tn) {
      float xv = xn[tt*Dn + c];
      aq = fmaf(xv, wqa[j], aq);
      ak = fmaf(xv, wka[j], ak);
      av = fmaf(xv, wva[j], av);
    }
  }
  qin[t*Dn + c] = aq;
  kin[t*Dn + c] = ak;
  vin[t*Dn + c] = av;
}

// ---------------------------------------------------------------------------
// K3: fp32 NT GEMM  C[m,n] = sum_k A[m,k]*B[n,k]   (512^3)
// ---------------------------------------------------------------------------
__global__ __launch_bounds__(256) void k_gemm_nt(
    const float* __restrict__ Abase, long sA,
    const float* __restrict__ B0, const float* __restrict__ B1,
    const float* __restrict__ B2,
    float* __restrict__ Cbase, long sC)
{
  const int z = blockIdx.z;
  const float* A = Abase + (long)z * sA;
  const float* B = (z == 0) ? B0 : (z == 1) ? B1 : B2;
  float* C = Cbase + (long)z * sC;
  __shared__ float As[16][65];
  __shared__ float Bs[16][65];
  const int tid = threadIdx.x;
  const int m0 = blockIdx.x * 64, n0 = blockIdx.y * 64;
  const int lr_ = tid >> 2;
  const int lc_ = (tid & 3) << 2;
  const int ty = tid >> 4, tx = tid & 15;
  float acc[4][4] = {{0.f}};
  for (int k0 = 0; k0 < 512; k0 += 16) {
    float4 avv = *(const float4*)&A[(m0 + lr_)*512 + k0 + lc_];
    float4 bvv = *(const float4*)&B[(n0 + lr_)*512 + k0 + lc_];
    As[lc_+0][lr_] = avv.x; As[lc_+1][lr_] = avv.y;
    As[lc_+2][lr_] = avv.z; As[lc_+3][lr_] = avv.w;
    Bs[lc_+0][lr_] = bvv.x; Bs[lc_+1][lr_] = bvv.y;
    Bs[lc_+2][lr_] = bvv.z; Bs[lc_+3][lr_] = bvv.w;
    __syncthreads();
    #pragma unroll
    for (int k = 0; k < 16; ++k) {
      float a[4], b[4];
      #pragma unroll
      for (int i = 0; i < 4; ++i) a[i] = As[k][ty*4 + i];
      #pragma unroll
      for (int j = 0; j < 4; ++j) b[j] = Bs[k][tx*4 + j];
      #pragma unroll
      for (int i = 0; i < 4; ++i)
        #pragma unroll
        for (int j = 0; j < 4; ++j) acc[i][j] = fmaf(a[i], b[j], acc[i][j]);
    }
    __syncthreads();
  }
  #pragma unroll
  for (int i = 0; i < 4; ++i)
    #pragma unroll
    for (int j = 0; j < 4; ++j)
      C[(m0 + ty*4 + i)*512 + (n0 + tx*4 + j)] = acc[i][j];
}

// ---------------------------------------------------------------------------
// K4: per-head RMS norm of Q and K (in place)
// ---------------------------------------------------------------------------
__global__ __launch_bounds__(64) void k_mhrms(
    float* __restrict__ Qb, float* __restrict__ Kb,
    const float* __restrict__ qg, const float* __restrict__ kg)
{
  const int h = blockIdx.x, t = blockIdx.y, z = blockIdx.z, d = threadIdx.x;
  float* base = z ? Kb : Qb;
  const float* gm = z ? kg : qg;
  const int idx = t*Dn + h*DHn + d;
  float v = base[idx];
  float ss = v * v;
  #pragma unroll
  for (int o = 1; o < 64; o <<= 1) ss += __shfl_xor(ss, o, 64);
  float rms = sqrtf(ss) * 0.125f;
  base[idx] = v / fmaxf(rms, 1e-8f) * gm[h*DHn + d];
}

// ---------------------------------------------------------------------------
// K5a: per-chunk local prefixes (phase 1).
// Block (c,h), 256 threads: thread owns row=tid>>2, cols c0..c0+15 (c0=(tid&3)*16)
// of M (A-prefix, init I) and N (C-prefix, init 0). Per step (time t):
//   uM[s]=M_row.k_s, uN[s]=N_row.k_s (4-lane reduce);
//   M = dc*M + sum_s(-dc*w_s*uM_s) k_s ;  N = dc*N + sum_s w_s(v_s[row]-dc*uN_s) k_s
// After update: z_t = M q_t, chat_t = N q_t (stored per t).
// Final M,N -> Abar,Cbar (chunk transfer operators).
// ---------------------------------------------------------------------------
__global__ __launch_bounds__(256) void k_chunk(
    const float* __restrict__ Qn, const float* __restrict__ Kn,
    const float* __restrict__ V,
    const float* __restrict__ wgt, const float* __restrict__ dec,
    float* __restrict__ Abar, float* __restrict__ Cbar,
    float* __restrict__ zbuf, float* __restrict__ cbuf)
{
  const int c = blockIdx.x, h = blockIdx.y;
  const int tid = threadIdx.x;
  const int row = tid >> 2, g = tid & 3, c0 = g * 16;
  __shared__ float kring[8][64];
  __shared__ float qrow[64];

  float M[16], Nn[16];
  #pragma unroll
  for (int j = 0; j < 16; ++j) {
    M[j] = (row == c0 + j) ? 1.f : 0.f;
    Nn[j] = 0.f;
  }
  float vw[8], ww[8];
  vw[0] = 0.f; ww[0] = 0.f;
  // preload window times c*CL-7 .. c*CL-1 into slots 1..7 (CL multiple of 8)
  #pragma unroll
  for (int i = 0; i < 7; ++i) {
    const int t = c * CL - 7 + i;
    const int slot = i + 1;
    if (t >= 0) {
      if (tid < 64) kring[slot][tid] = Kn[t*Dn + h*DHn + tid];
      vw[slot] = V[t*Dn + h*DHn + row];
      ww[slot] = wgt[h*Tn + t];
    } else {
      if (tid < 64) kring[slot][tid] = 0.f;
      vw[slot] = 0.f; ww[slot] = 0.f;
    }
  }

  for (int ib = 0; ib < 2; ++ib) {
    #pragma unroll
    for (int ii = 0; ii < 8; ++ii) {
      const int t = c * CL + ib * 8 + ii;
      // stage current k,q into LDS; v,w into ring regs
      if (tid < 64) kring[ii][tid] = Kn[t*Dn + h*DHn + tid];
      else if (tid < 128) qrow[tid - 64] = Qn[t*Dn + h*DHn + (tid - 64)];
      vw[ii] = V[t*Dn + h*DHn + row];
      ww[ii] = wgt[h*Tn + t];
      const float dc = dec[h*Tn + t];
      __syncthreads();

      // u-pass (old M,N)
      float uM[8], uN[8];
      #pragma unroll
      for (int s = 0; s < 8; ++s) {
        float kk[16];
        const float4* kr = (const float4*)&kring[s][c0];
        *(float4*)&kk[0]  = kr[0]; *(float4*)&kk[4]  = kr[1];
        *(float4*)&kk[8]  = kr[2]; *(float4*)&kk[12] = kr[3];
        float a = 0.f, b = 0.f;
        #pragma unroll
        for (int j = 0; j < 16; ++j) {
          a = fmaf(M[j], kk[j], a);
          b = fmaf(Nn[j], kk[j], b);
        }
        uM[s] = a; uN[s] = b;
      }
      #pragma unroll
      for (int s = 0; s < 8; ++s) {
        uM[s] += __shfl_xor(uM[s], 1, 64); uM[s] += __shfl_xor(uM[s], 2, 64);
        uN[s] += __shfl_xor(uN[s], 1, 64); uN[s] += __shfl_xor(uN[s], 2, 64);
      }

      // update
      #pragma unroll
      for (int j = 0; j < 16; ++j) { M[j] *= dc; Nn[j] *= dc; }
      #pragma unroll
      for (int s = 0; s < 8; ++s) {
        const float cM = -dc * ww[s] * uM[s];
        const float cN = ww[s] * (vw[s] - dc * uN[s]);
        float kk[16];
        const float4* kr = (const float4*)&kring[s][c0];
        *(float4*)&kk[0]  = kr[0]; *(float4*)&kk[4]  = kr[1];
        *(float4*)&kk[8]  = kr[2]; *(float4*)&kk[12] = kr[3];
        #pragma unroll
        for (int j = 0; j < 16; ++j) {
          M[j]  = fmaf(cM, kk[j], M[j]);
          Nn[j] = fmaf(cN, kk[j], Nn[j]);
        }
      }

      // z_t = M q_t, chat_t = N q_t (post-update prefixes)
      {
        float kq[16];
        const float4* qr = (const float4*)&qrow[c0];
        *(float4*)&kq[0]  = qr[0]; *(float4*)&kq[4]  = qr[1];
        *(float4*)&kq[8]  = qr[2]; *(float4*)&kq[12] = qr[3];
        float zp = 0.f, cp = 0.f;
        #pragma unroll
        for (int j = 0; j < 16; ++j) {
          zp = fmaf(M[j], kq[j], zp);
          cp = fmaf(Nn[j], kq[j], cp);
        }
        zp += __shfl_xor(zp, 1, 64); zp += __shfl_xor(zp, 2, 64);
        cp += __shfl_xor(cp, 1, 64); cp += __shfl_xor(cp, 2, 64);
        if (g == 0) {
          zbuf[(h*Tn + t)*DHn + row] = zp;
          cbuf[(h*Tn + t)*DHn + row] = cp;
        }
      }
      __syncthreads();
    }
  }
  float* Ao = Abar + (((long)(c*NH + h)) * 64 + row) * 64 + c0;
  float* Co = Cbar + (((long)(c*NH + h)) * 64 + row) * 64 + c0;
  #pragma unroll
  for (int j4 = 0; j4 < 4; ++j4) {
    *(float4*)&Ao[j4*4] = *(float4*)&M[j4*4];
    *(float4*)&Co[j4*4] = *(float4*)&Nn[j4*4];
  }
}

// ---------------------------------------------------------------------------
// K5b: sequential chunk-level scan + output (phases 2+3).
// Block (h,m), 64 lanes: lane d holds S_start[m][d]. Per chunk c:
//   y_t = s . z_t + chat_t[m]  (t in chunk, via readlane-broadcast of s)
//   s <- s @ Abar_c + Cbar_c[m]
// ---------------------------------------------------------------------------
__global__ __launch_bounds__(64) void k_scan(
    const float* __restrict__ Abar, const float* __restrict__ Cbar,
    const float* __restrict__ zbuf, const float* __restrict__ cbuf,
    const float* __restrict__ S0, float* __restrict__ Y)
{
  const int h = blockIdx.x >> 6, m = blockIdx.x & 63, d = threadIdx.x;
  const int tt = d >> 2, j = d & 3;
  float s = S0[(h*DHn + m)*DHn + d];
  for (int c = 0; c < NC; ++c) {
    const float* Ac = Abar + (long)(c*NH + h) * 4096;
    const float* Cb = Cbar + (long)(c*NH + h) * 4096;
    const float* Zc = zbuf + (long)(h*Tn + c*CL) * DHn;
    const float* Cc = cbuf + (long)(h*Tn + c*CL) * DHn;
    float nsp[4] = {0.f, 0.f, 0.f, 0.f};
    float yp[4]  = {0.f, 0.f, 0.f, 0.f};
    #pragma unroll
    for (int gq = 0; gq < 4; ++gq) {
      float sv[16];
      #pragma unroll
      for (int l = 0; l < 16; ++l) sv[l] = rdlane(s, gq*16 + l);
      #pragma unroll
      for (int l = 0; l < 16; ++l)
        nsp[gq] = fmaf(sv[l], Ac[(gq*16 + l)*64 + d], nsp[gq]);
      #pragma unroll
      for (int i2 = 0; i2 < 4; ++i2)
        yp[gq] = fmaf(sv[j + 4*i2], Zc[tt*DHn + gq*16 + j + 4*i2], yp[gq]);
    }
    float yacc = (yp[0] + yp[1]) + (yp[2] + yp[3]);
    yacc += __shfl_xor(yacc, 1, 64);
    yacc += __shfl_xor(yacc, 2, 64);
    if (j == 0) {
      const int t = c*CL + tt;
      Y[t*Dn + h*DHn + m] = yacc + Cc[tt*DHn + m];
    }
    s = ((nsp[0] + nsp[1]) + (nsp[2] + nsp[3])) + Cb[m*DHn + d];
  }
}

// ---------------------------------------------------------------------------
extern "C" void kernel_launch(void* const* d_in, const int* in_sizes, int n_in,
                              void* d_out, int out_size, void* d_ws, size_t ws_size,
                              hipStream_t stream)
{
  const float* x   = (const float*)d_in[0];
  const float* pw  = (const float*)d_in[1];
  const float* Wq  = (const float*)d_in[2];
  const float* Wk  = (const float*)d_in[3];
  const float* Wv  = (const float*)d_in[4];
  const float* Wo  = (const float*)d_in[5];
  const float* qcw = (const float*)d_in[6];
  const float* kcw = (const float*)d_in[7];
  const float* vcw = (const float*)d_in[8];
  const float* lrw = (const float*)d_in[9];
  const float* lrb = (const float*)d_in[10];
  const float* dw  = (const float*)d_in[11];
  const float* db  = (const float*)d_in[12];
  const float* gw  = (const float*)d_in[13];
  const float* gb  = (const float*)d_in[14];
  const float* qg  = (const float*)d_in[15];
  const float* kg  = (const float*)d_in[16];
  const float* S0  = (const float*)d_in[17];
  float* out = (float*)d_out;
  float* ws  = (float*)d_ws;

  const long N = (long)Tn * Dn;   // 262144
  // region [0,4N): xn/qin/kin/vin, dead after GEMM1 -> reused as Abar
  float* xn  = ws;
  float* qin = ws + 1*N;
  float* kin = ws + 2*N;
  float* vin = ws + 3*N;
  float* Abar = ws;               // overlay (32*8*4096 = 4N floats)
  float* Qb  = ws + 4*N;
  float* Kb  = ws + 5*N;
  float* Vb  = ws + 6*N;
  float* Yb  = ws + 7*N;
  float* wgt = ws + 8*N;              // [NH][T]
  float* dcb = wgt + NH*Tn;           // [NH][T]
  float* Cbar = dcb + NH*Tn;          // 4N floats
  float* zbuf = Cbar + 4*N;           // N floats [h][t][d]
  float* cbuf = zbuf + N;             // N floats [h][t][d]

  k_norm_gates<<<Tn, 256, 0, stream>>>(x, pw, lrw, lrb, dw, db, gw, gb,
                                       xn, wgt, dcb);
  k_conv<<<Tn, Dn, 0, stream>>>(xn, qcw, kcw, vcw, qin, kin, vin);
  k_gemm_nt<<<dim3(8, 8, 3), 256, 0, stream>>>(qin, N, Wq, Wk, Wv, Qb, N);
  k_mhrms<<<dim3(NH, Tn, 2), 64, 0, stream>>>(Qb, Kb, qg, kg);
  k_chunk<<<dim3(NC, NH), 256, 0, stream>>>(Qb, Kb, Vb, wgt, dcb,
                                            Abar, Cbar, zbuf, cbuf);
  k_scan<<<NH * DHn, 64, 0, stream>>>(Abar, Cbar, zbuf, cbuf, S0, Yb);
  k_gemm_nt<<<dim3(8, 8, 1), 256, 0, stream>>>(Yb, 0, Wo, Wo, Wo, out, 0);
}

// Round 9
// 227.986 us; speedup vs baseline: 2.7685x; 1.3255x over previous
//
#include <hip/hip_runtime.h>
#include <math.h>

constexpr int Tn  = 512;
constexpr int Dn  = 512;   // DIM
constexpr int NH  = 8;
constexpr int DHn = 64;
constexpr int CL  = 16;    // chunk length
constexpr int NC  = Tn / CL; // 32 chunks
constexpr float EPSR = 1.1920929e-07f;

static __device__ __forceinline__ float rdlane(float v, int l) {
  return __uint_as_float((unsigned)__builtin_amdgcn_readlane((int)__float_as_uint(v), l));
}

// ---------------------------------------------------------------------------
// K1: pre RMSNorm + the three sigmoid gates (lr, decay, omega)
// ---------------------------------------------------------------------------
__global__ __launch_bounds__(256) void k_norm_gates(
    const float* __restrict__ x, const float* __restrict__ pw,
    const float* __restrict__ lrw, const float* __restrict__ lrb,
    const float* __restrict__ dw,  const float* __restrict__ db,
    const float* __restrict__ gw,  const float* __restrict__ gb,
    float* __restrict__ xn, float* __restrict__ wgt, float* __restrict__ dec)
{
  const int t = blockIdx.x;
  const int tid = threadIdx.x;
  const int lane = tid & 63, wid = tid >> 6;
  __shared__ float xrow[Dn];
  __shared__ float red[4];
  __shared__ float gl[24];

  float v0 = x[t*Dn + tid];
  float v1 = x[t*Dn + 256 + tid];
  float ss = v0*v0 + v1*v1;
  #pragma unroll
  for (int o = 1; o < 64; o <<= 1) ss += __shfl_xor(ss, o, 64);
  if (lane == 0) red[wid] = ss;
  __syncthreads();
  float ms = (red[0] + red[1] + red[2] + red[3]) * (1.0f / Dn);
  float sc = rsqrtf(ms + EPSR);
  float xn0 = v0 * sc * pw[tid];
  float xn1 = v1 * sc * pw[tid + 256];
  xrow[tid] = xn0; xrow[tid + 256] = xn1;
  xn[t*Dn + tid] = xn0; xn[t*Dn + 256 + tid] = xn1;
  __syncthreads();

  for (int g = wid; g < 24; g += 4) {
    const float* W = (g < 8) ? lrw : (g < 16) ? dw : gw;
    const int hh = g & 7;
    float acc = 0.f;
    #pragma unroll
    for (int j = 0; j < 8; ++j)
      acc += xrow[lane + j*64] * W[hh*Dn + lane + j*64];
    #pragma unroll
    for (int o = 1; o < 64; o <<= 1) acc += __shfl_xor(acc, o, 64);
    if (lane == 0) {
      float bias = ((g < 8) ? lrb : (g < 16) ? db : gb)[hh];
      gl[g] = 1.f / (1.f + __expf(-(acc + bias)));
    }
  }
  __syncthreads();
  if (tid < 8)        wgt[tid*Tn + t] = gl[16 + tid] * gl[tid];  // omega * lr
  else if (tid < 16)  dec[(tid - 8)*Tn + t] = gl[tid];           // decay
}

// ---------------------------------------------------------------------------
// K2: depthwise conv1d (K=4)
// ---------------------------------------------------------------------------
__global__ __launch_bounds__(512) void k_conv(
    const float* __restrict__ xn,
    const float* __restrict__ qcw, const float* __restrict__ kcw,
    const float* __restrict__ vcw,
    float* __restrict__ qin, float* __restrict__ kin, float* __restrict__ vin)
{
  const int t = blockIdx.x, c = threadIdx.x;
  float4 wq = *(const float4*)&qcw[c*4];
  float4 wk = *(const float4*)&kcw[c*4];
  float4 wv = *(const float4*)&vcw[c*4];
  float wqa[4] = {wq.x, wq.y, wq.z, wq.w};
  float wka[4] = {wk.x, wk.y, wk.z, wk.w};
  float wva[4] = {wv.x, wv.y, wv.z, wv.w};
  float aq = 0.f, ak = 0.f, av = 0.f;
  #pragma unroll
  for (int j = 0; j < 4; ++j) {
    int tt = t - 2 + j;
    if (tt >= 0 && tt < Tn) {
      float xv = xn[tt*Dn + c];
      aq = fmaf(xv, wqa[j], aq);
      ak = fmaf(xv, wka[j], ak);
      av = fmaf(xv, wva[j], av);
    }
  }
  qin[t*Dn + c] = aq;
  kin[t*Dn + c] = ak;
  vin[t*Dn + c] = av;
}

// ---------------------------------------------------------------------------
// K3: fp32 NT GEMM  C[m,n] = sum_k A[m,k]*B[n,k]  (512^3)
// Optional fused per-head RMS (gamma != null, head = blockIdx.y since DH==64):
// row r (a time step) normalized over the 64 cols of this tile.
// ---------------------------------------------------------------------------
__global__ __launch_bounds__(256) void k_gemm_nt(
    const float* __restrict__ Abase, long sA,
    const float* __restrict__ B0, const float* __restrict__ B1,
    const float* __restrict__ B2,
    float* __restrict__ Cbase, long sC,
    const float* __restrict__ gA, const float* __restrict__ gB)
{
  const int z = blockIdx.z;
  const float* A = Abase + (long)z * sA;
  const float* B = (z == 0) ? B0 : (z == 1) ? B1 : B2;
  float* C = Cbase + (long)z * sC;
  __shared__ float As[16][65];
  __shared__ float Bs[16][65];
  const int tid = threadIdx.x;
  const int m0 = blockIdx.x * 64, n0 = blockIdx.y * 64;
  const int lr_ = tid >> 2;
  const int lc_ = (tid & 3) << 2;
  const int ty = tid >> 4, tx = tid & 15;
  float acc[4][4] = {{0.f}};
  for (int k0 = 0; k0 < 512; k0 += 16) {
    float4 avv = *(const float4*)&A[(m0 + lr_)*512 + k0 + lc_];
    float4 bvv = *(const float4*)&B[(n0 + lr_)*512 + k0 + lc_];
    As[lc_+0][lr_] = avv.x; As[lc_+1][lr_] = avv.y;
    As[lc_+2][lr_] = avv.z; As[lc_+3][lr_] = avv.w;
    Bs[lc_+0][lr_] = bvv.x; Bs[lc_+1][lr_] = bvv.y;
    Bs[lc_+2][lr_] = bvv.z; Bs[lc_+3][lr_] = bvv.w;
    __syncthreads();
    #pragma unroll
    for (int k = 0; k < 16; ++k) {
      float a[4], b[4];
      #pragma unroll
      for (int i = 0; i < 4; ++i) a[i] = As[k][ty*4 + i];
      #pragma unroll
      for (int j = 0; j < 4; ++j) b[j] = Bs[k][tx*4 + j];
      #pragma unroll
      for (int i = 0; i < 4; ++i)
        #pragma unroll
        for (int j = 0; j < 4; ++j) acc[i][j] = fmaf(a[i], b[j], acc[i][j]);
    }
    __syncthreads();
  }
  const float* gm = (z == 0) ? gA : (z == 1) ? gB : nullptr;
  if (gm != nullptr) {
    #pragma unroll
    for (int i = 0; i < 4; ++i) {
      float ss = 0.f;
      #pragma unroll
      for (int j = 0; j < 4; ++j) ss += acc[i][j] * acc[i][j];
      ss += __shfl_xor(ss, 1, 64); ss += __shfl_xor(ss, 2, 64);
      ss += __shfl_xor(ss, 4, 64); ss += __shfl_xor(ss, 8, 64);
      float rms = sqrtf(ss) * 0.125f;            // ||x|| * 64^-0.5
      float inv = 1.f / fmaxf(rms, 1e-8f);
      #pragma unroll
      for (int j = 0; j < 4; ++j)
        acc[i][j] *= inv * gm[blockIdx.y*DHn + tx*4 + j];
    }
  }
  #pragma unroll
  for (int i = 0; i < 4; ++i)
    #pragma unroll
    for (int j = 0; j < 4; ++j)
      C[(m0 + ty*4 + i)*512 + (n0 + tx*4 + j)] = acc[i][j];
}

// ---------------------------------------------------------------------------
// K5a: per-chunk local prefixes. Block (c,h), 256 threads, NO LDS / NO SYNC:
// thread owns row=tid>>2, cols c0..c0+15 of M (A-prefix, init I) and N
// (C-prefix, init 0). k-ring kept in registers (kk[8][16]), one slot
// refreshed per step from global (L2-hot). 4-lane shuffle reduces only.
// Emits z_t = M_t q_t, chat_t = N_t q_t and final M,N -> Abar,Cbar.
// ---------------------------------------------------------------------------
__global__ __launch_bounds__(256, 1) void k_chunk(
    const float* __restrict__ Qn, const float* __restrict__ Kn,
    const float* __restrict__ V,
    const float* __restrict__ wgt, const float* __restrict__ dec,
    float* __restrict__ Abar, float* __restrict__ Cbar,
    float* __restrict__ zbuf, float* __restrict__ cbuf)
{
  const int c = blockIdx.x, h = blockIdx.y;
  const int tid = threadIdx.x;
  const int row = tid >> 2, g = tid & 3, c0 = g * 16;

  float M[16], Nn[16], kk[8][16], vw[8], ww[8];
  #pragma unroll
  for (int j = 0; j < 16; ++j) {
    M[j] = (row == c0 + j) ? 1.f : 0.f;
    Nn[j] = 0.f;
  }
  #pragma unroll
  for (int j = 0; j < 16; ++j) kk[0][j] = 0.f;
  vw[0] = 0.f; ww[0] = 0.f;
  #pragma unroll
  for (int i = 0; i < 7; ++i) {
    const int t = c * CL - 7 + i;
    const int slot = i + 1;
    if (t >= 0) {
      const float4* kr = (const float4*)(Kn + (long)t*Dn + h*DHn + c0);
      #pragma unroll
      for (int j4 = 0; j4 < 4; ++j4) *(float4*)&kk[slot][j4*4] = kr[j4];
      vw[slot] = V[(long)t*Dn + h*DHn + row];
      ww[slot] = wgt[h*Tn + t];
    } else {
      #pragma unroll
      for (int j = 0; j < 16; ++j) kk[slot][j] = 0.f;
      vw[slot] = 0.f; ww[slot] = 0.f;
    }
  }

  for (int tb = 0; tb < 2; ++tb) {
    #pragma unroll
    for (int ii = 0; ii < 8; ++ii) {
      const int t = c * CL + tb * 8 + ii;
      // refresh ring slot ii (replaces t-8) with time t
      {
        const float4* kr = (const float4*)(Kn + (long)t*Dn + h*DHn + c0);
        #pragma unroll
        for (int j4 = 0; j4 < 4; ++j4) *(float4*)&kk[ii][j4*4] = kr[j4];
      }
      vw[ii] = V[(long)t*Dn + h*DHn + row];
      ww[ii] = wgt[h*Tn + t];
      const float dc = dec[h*Tn + t];

      // u-pass on OLD M,N
      float uM[8], uN[8];
      #pragma unroll
      for (int s = 0; s < 8; ++s) {
        float a = 0.f, b = 0.f;
        #pragma unroll
        for (int j = 0; j < 16; ++j) {
          a = fmaf(M[j], kk[s][j], a);
          b = fmaf(Nn[j], kk[s][j], b);
        }
        a += __shfl_xor(a, 1, 64); a += __shfl_xor(a, 2, 64);
        b += __shfl_xor(b, 1, 64); b += __shfl_xor(b, 2, 64);
        uM[s] = a; uN[s] = b;
      }
      // update
      #pragma unroll
      for (int j = 0; j < 16; ++j) { M[j] *= dc; Nn[j] *= dc; }
      #pragma unroll
      for (int s = 0; s < 8; ++s) {
        const float cM = -dc * ww[s] * uM[s];
        const float cN = ww[s] * (vw[s] - dc * uN[s]);
        #pragma unroll
        for (int j = 0; j < 16; ++j) {
          M[j]  = fmaf(cM, kk[s][j], M[j]);
          Nn[j] = fmaf(cN, kk[s][j], Nn[j]);
        }
      }
      // z_t = M q_t, chat_t = N q_t
      {
        float qv[16];
        const float4* qr = (const float4*)(Qn + (long)t*Dn + h*DHn + c0);
        #pragma unroll
        for (int j4 = 0; j4 < 4; ++j4) *(float4*)&qv[j4*4] = qr[j4];
        float zp = 0.f, cp = 0.f;
        #pragma unroll
        for (int j = 0; j < 16; ++j) {
          zp = fmaf(M[j], qv[j], zp);
          cp = fmaf(Nn[j], qv[j], cp);
        }
        zp += __shfl_xor(zp, 1, 64); zp += __shfl_xor(zp, 2, 64);
        cp += __shfl_xor(cp, 1, 64); cp += __shfl_xor(cp, 2, 64);
        if (g == 0) {
          zbuf[((long)h*Tn + t)*DHn + row] = zp;
          cbuf[((long)h*Tn + t)*DHn + row] = cp;
        }
      }
    }
  }
  float* Ao = Abar + (((long)(c*NH + h)) * 64 + row) * 64 + c0;
  float* Co = Cbar + (((long)(c*NH + h)) * 64 + row) * 64 + c0;
  #pragma unroll
  for (int j4 = 0; j4 < 4; ++j4) {
    *(float4*)&Ao[j4*4] = *(float4*)&M[j4*4];
    *(float4*)&Co[j4*4] = *(float4*)&Nn[j4*4];
  }
}

// ---------------------------------------------------------------------------
// K5b: state-only chunk scan with register double-buffer prefetch.
// Block (h,m), 64 lanes: lane d holds s[d]. Stores S_start per chunk.
// ---------------------------------------------------------------------------
__global__ __launch_bounds__(64, 1) void k_scan(
    const float* __restrict__ Abar, const float* __restrict__ Cbar,
    const float* __restrict__ S0, float* __restrict__ Sst)
{
  const int h = blockIdx.x >> 6, m = blockIdx.x & 63, d = threadIdx.x;
  float s = S0[((long)h*DHn + m)*DHn + d];
  float a0[64], a1[64];
  float cb0, cb1;

#define PREF_(AR, CB, CI) do { \
    const float* Ac_ = Abar + ((long)(CI)*NH + h) * 4096; \
    _Pragma("unroll") \
    for (int l = 0; l < 64; ++l) AR[l] = Ac_[l*64 + d]; \
    CB = Cbar[((long)(CI)*NH + h) * 4096 + m*64 + d]; \
  } while (0)

#define STEP_(AR, CB) do { \
    float n0 = 0.f, n1 = 0.f, n2 = 0.f, n3 = 0.f; \
    _Pragma("unroll") \
    for (int l = 0; l < 16; ++l) { \
      n0 = fmaf(rdlane(s, l),      AR[l],      n0); \
      n1 = fmaf(rdlane(s, 16 + l), AR[16 + l], n1); \
      n2 = fmaf(rdlane(s, 32 + l), AR[32 + l], n2); \
      n3 = fmaf(rdlane(s, 48 + l), AR[48 + l], n3); \
    } \
    s = ((n0 + n1) + (n2 + n3)) + CB; \
  } while (0)

  PREF_(a0, cb0, 0);
  #pragma unroll 1
  for (int c = 0; c < NC; c += 2) {
    PREF_(a1, cb1, c + 1);
    Sst[(((long)c*NH + h)*64 + m)*64 + d] = s;
    STEP_(a0, cb0);
    const int cn = (c + 2 < NC) ? (c + 2) : (NC - 1);
    PREF_(a0, cb0, cn);
    Sst[(((long)(c+1)*NH + h)*64 + m)*64 + d] = s;
    STEP_(a1, cb1);
  }
#undef PREF_
#undef STEP_
}

// ---------------------------------------------------------------------------
// K5c: parallel output eval. Block (c,h), 256 thr:
// y_t[m] = Sst_c[m,:] . z_t + chat_t[m]  for the chunk's 16 t's.
// ---------------------------------------------------------------------------
__global__ __launch_bounds__(256, 1) void k_yout(
    const float* __restrict__ Sst, const float* __restrict__ zbuf,
    const float* __restrict__ cbuf, float* __restrict__ Y)
{
  const int c = blockIdx.x, h = blockIdx.y;
  const int tid = threadIdx.x, m = tid & 63, tg = tid >> 6;
  __shared__ float Zl[CL][DHn];
  {
    const float4* Zc = (const float4*)(zbuf + ((long)h*Tn + c*CL) * DHn);
    ((float4*)&Zl[0][0])[tid] = Zc[tid];
  }
  const float* Srow = Sst + (((long)c*NH + h)*64 + m) * 64;
  float sr[64];
  #pragma unroll
  for (int q4 = 0; q4 < 16; ++q4)
    *(float4*)&sr[q4*4] = ((const float4*)Srow)[q4];
  __syncthreads();
  const float* Cc = cbuf + ((long)h*Tn + c*CL) * DHn;
  #pragma unroll
  for (int it = 0; it < 4; ++it) {
    const int tt = tg*4 + it;
    float y = 0.f;
    #pragma unroll
    for (int l = 0; l < 64; ++l) y = fmaf(sr[l], Zl[tt][l], y);
    Y[((long)(c*CL + tt))*Dn + h*DHn + m] = y + Cc[tt*DHn + m];
  }
}

// ---------------------------------------------------------------------------
extern "C" void kernel_launch(void* const* d_in, const int* in_sizes, int n_in,
                              void* d_out, int out_size, void* d_ws, size_t ws_size,
                              hipStream_t stream)
{
  const float* x   = (const float*)d_in[0];
  const float* pw  = (const float*)d_in[1];
  const float* Wq  = (const float*)d_in[2];
  const float* Wk  = (const float*)d_in[3];
  const float* Wv  = (const float*)d_in[4];
  const float* Wo  = (const float*)d_in[5];
  const float* qcw = (const float*)d_in[6];
  const float* kcw = (const float*)d_in[7];
  const float* vcw = (const float*)d_in[8];
  const float* lrw = (const float*)d_in[9];
  const float* lrb = (const float*)d_in[10];
  const float* dw  = (const float*)d_in[11];
  const float* db  = (const float*)d_in[12];
  const float* gw  = (const float*)d_in[13];
  const float* gb  = (const float*)d_in[14];
  const float* qg  = (const float*)d_in[15];
  const float* kg  = (const float*)d_in[16];
  const float* S0  = (const float*)d_in[17];
  float* out = (float*)d_out;
  float* ws  = (float*)d_ws;

  const long N = (long)Tn * Dn;   // 262144
  // [0,4N):  xn/qin/kin/vin  ->  Abar (after GEMM1)  ->  Yb over [0,N) (after k_scan)
  // [4N,8N): Qb/Kb/Vb (+spare) -> Sst (after k_chunk)
  float* xn   = ws;
  float* qin  = ws + 1*N;
  float* kin  = ws + 2*N;
  float* vin  = ws + 3*N;
  float* Abar = ws;
  float* Yb   = ws;
  float* Qb   = ws + 4*N;
  float* Kb   = ws + 5*N;
  float* Vb   = ws + 6*N;
  float* Sst  = ws + 4*N;
  float* wgt  = ws + 8*N;             // [NH][T]
  float* dcb  = wgt + NH*Tn;          // [NH][T]
  float* Cbar = dcb + NH*Tn;          // 4N floats
  float* zbuf = Cbar + 4*N;           // N floats [h][t][d]
  float* cbuf = zbuf + N;             // N floats [h][t][d]

  k_norm_gates<<<Tn, 256, 0, stream>>>(x, pw, lrw, lrb, dw, db, gw, gb,
                                       xn, wgt, dcb);
  k_conv<<<Tn, Dn, 0, stream>>>(xn, qcw, kcw, vcw, qin, kin, vin);
  k_gemm_nt<<<dim3(8, 8, 3), 256, 0, stream>>>(qin, N, Wq, Wk, Wv, Qb, N, qg, kg);
  k_chunk<<<dim3(NC, NH), 256, 0, stream>>>(Qb, Kb, Vb, wgt, dcb,
                                            Abar, Cbar, zbuf, cbuf);
  k_scan<<<NH * DHn, 64, 0, stream>>>(Abar, Cbar, S0, Sst);
  k_yout<<<dim3(NC, NH), 256, 0, stream>>>(Sst, zbuf, cbuf, Yb);
  k_gemm_nt<<<dim3(8, 8, 1), 256, 0, stream>>>(Yb, 0, Wo, Wo, Wo, out, 0,
                                               nullptr, nullptr);
}

// Round 10
// 172.292 us; speedup vs baseline: 3.6634x; 1.3233x over previous
//
#include <hip/hip_runtime.h>
#include <math.h>

constexpr int Tn  = 512;
constexpr int Dn  = 512;   // DIM
constexpr int NH  = 8;
constexpr int DHn = 64;
constexpr int CL  = 16;    // chunk length
constexpr int NC  = Tn / CL; // 32 chunks
constexpr int NW  = Tn * Dn; // one 512x512 matrix
constexpr float EPSR = 1.1920929e-07f;

typedef __attribute__((ext_vector_type(8))) short bf16x8;
typedef __attribute__((ext_vector_type(4))) float f32x4;

static __device__ __forceinline__ float rdlane(float v, int l) {
  return __uint_as_float((unsigned)__builtin_amdgcn_readlane((int)__float_as_uint(v), l));
}
static __device__ __forceinline__ ushort f2bf(float f) {
  unsigned u = __float_as_uint(f);
  unsigned r = u + 0x7FFFu + ((u >> 16) & 1u);   // RNE
  return (ushort)(r >> 16);
}

// ---------------------------------------------------------------------------
// K1: pre RMSNorm + the three sigmoid gates (lr, decay, omega)
// ---------------------------------------------------------------------------
__global__ __launch_bounds__(256) void k_norm_gates(
    const float* __restrict__ x, const float* __restrict__ pw,
    const float* __restrict__ lrw, const float* __restrict__ lrb,
    const float* __restrict__ dw,  const float* __restrict__ db,
    const float* __restrict__ gw,  const float* __restrict__ gb,
    float* __restrict__ xn, float* __restrict__ wgt, float* __restrict__ dec)
{
  const int t = blockIdx.x;
  const int tid = threadIdx.x;
  const int lane = tid & 63, wid = tid >> 6;
  __shared__ float xrow[Dn];
  __shared__ float red[4];
  __shared__ float gl[24];

  float v0 = x[t*Dn + tid];
  float v1 = x[t*Dn + 256 + tid];
  float ss = v0*v0 + v1*v1;
  #pragma unroll
  for (int o = 1; o < 64; o <<= 1) ss += __shfl_xor(ss, o, 64);
  if (lane == 0) red[wid] = ss;
  __syncthreads();
  float ms = (red[0] + red[1] + red[2] + red[3]) * (1.0f / Dn);
  float sc = rsqrtf(ms + EPSR);
  float xn0 = v0 * sc * pw[tid];
  float xn1 = v1 * sc * pw[tid + 256];
  xrow[tid] = xn0; xrow[tid + 256] = xn1;
  xn[t*Dn + tid] = xn0; xn[t*Dn + 256 + tid] = xn1;
  __syncthreads();

  for (int g = wid; g < 24; g += 4) {
    const float* W = (g < 8) ? lrw : (g < 16) ? dw : gw;
    const int hh = g & 7;
    float acc = 0.f;
    #pragma unroll
    for (int j = 0; j < 8; ++j)
      acc += xrow[lane + j*64] * W[hh*Dn + lane + j*64];
    #pragma unroll
    for (int o = 1; o < 64; o <<= 1) acc += __shfl_xor(acc, o, 64);
    if (lane == 0) {
      float bias = ((g < 8) ? lrb : (g < 16) ? db : gb)[hh];
      gl[g] = 1.f / (1.f + __expf(-(acc + bias)));
    }
  }
  __syncthreads();
  if (tid < 8)        wgt[tid*Tn + t] = gl[16 + tid] * gl[tid];  // omega * lr
  else if (tid < 16)  dec[(tid - 8)*Tn + t] = gl[tid];           // decay
}

// ---------------------------------------------------------------------------
// K1b: fp32 -> bf16 weight conversion (Wq,Wk,Wv,Wo -> Wbf[4][262144])
// ---------------------------------------------------------------------------
__global__ __launch_bounds__(256) void k_cvt_w(
    const float* __restrict__ W0, const float* __restrict__ W1,
    const float* __restrict__ W2, const float* __restrict__ W3,
    ushort* __restrict__ ob)
{
  const float* W = (blockIdx.y == 0) ? W0 : (blockIdx.y == 1) ? W1
                 : (blockIdx.y == 2) ? W2 : W3;
  ushort* o = ob + (long)blockIdx.y * NW;
  const int i = (blockIdx.x * 256 + threadIdx.x) * 4;
  float4 v = *(const float4*)&W[i];
  ushort4 r;
  r.x = f2bf(v.x); r.y = f2bf(v.y); r.z = f2bf(v.z); r.w = f2bf(v.w);
  *(ushort4*)&o[i] = r;
}

// ---------------------------------------------------------------------------
// K2: depthwise conv1d (K=4), bf16 outputs (GEMM operands)
// ---------------------------------------------------------------------------
__global__ __launch_bounds__(512) void k_conv(
    const float* __restrict__ xn,
    const float* __restrict__ qcw, const float* __restrict__ kcw,
    const float* __restrict__ vcw,
    ushort* __restrict__ qin, ushort* __restrict__ kin, ushort* __restrict__ vin)
{
  const int t = blockIdx.x, c = threadIdx.x;
  float4 wq = *(const float4*)&qcw[c*4];
  float4 wk = *(const float4*)&kcw[c*4];
  float4 wv = *(const float4*)&vcw[c*4];
  float wqa[4] = {wq.x, wq.y, wq.z, wq.w};
  float wka[4] = {wk.x, wk.y, wk.z, wk.w};
  float wva[4] = {wv.x, wv.y, wv.z, wv.w};
  float aq = 0.f, ak = 0.f, av = 0.f;
  #pragma unroll
  for (int j = 0; j < 4; ++j) {
    int tt = t - 2 + j;
    if (tt >= 0 && tt < Tn) {
      float xv = xn[tt*Dn + c];
      aq = fmaf(xv, wqa[j], aq);
      ak = fmaf(xv, wka[j], ak);
      av = fmaf(xv, wva[j], av);
    }
  }
  qin[t*Dn + c] = f2bf(aq);
  kin[t*Dn + c] = f2bf(ak);
  vin[t*Dn + c] = f2bf(av);
}

// ---------------------------------------------------------------------------
// K3: bf16 MFMA NT GEMM, fp32 out:  C[m,n] = sum_k A[m,k]*B[n,k]  (512^3)
// grid (16, 8, nz), 128 thr (2 waves). Wave w: rows bx*32+w*16..+16,
// cols by*64..+64 (4 16x16 tiles). No LDS: operands are L2-resident;
// fragments are contiguous bf16x8 loads (NT layout: lane l -> row l&15,
// k-window 8*(l>>4)). C/D: row=(l>>4)*4+r, col=l&15.
// Fused per-head RMS (gamma != null, head == blockIdx.y since DH==64).
// ---------------------------------------------------------------------------
__global__ __launch_bounds__(128) void k_gemm_bf(
    const ushort* __restrict__ A0, long sA,
    const ushort* __restrict__ B0, long sB,
    float* __restrict__ C0, long sC,
    const float* __restrict__ gq, const float* __restrict__ gk)
{
  const int z = blockIdx.z;
  const ushort* A = A0 + (long)z * sA;
  const ushort* B = B0 + (long)z * sB;
  float* C = C0 + (long)z * sC;
  const int w = threadIdx.x >> 6, l = threadIdx.x & 63;
  const int m0 = blockIdx.x * 32 + w * 16;
  const int n0 = blockIdx.y * 64;
  const int lr = l & 15, lk = (l >> 4) * 8;
  const ushort* ap = A + (long)(m0 + lr) * 512 + lk;
  const ushort* bp = B + (long)(n0 + lr) * 512 + lk;

  f32x4 acc0 = {0.f,0.f,0.f,0.f}, acc1 = {0.f,0.f,0.f,0.f};
  f32x4 acc2 = {0.f,0.f,0.f,0.f}, acc3 = {0.f,0.f,0.f,0.f};
  #pragma unroll
  for (int k0 = 0; k0 < 512; k0 += 32) {
    bf16x8 a  = *(const bf16x8*)(ap + k0);
    bf16x8 b0 = *(const bf16x8*)(bp + k0);
    bf16x8 b1 = *(const bf16x8*)(bp + 16*512 + k0);
    bf16x8 b2 = *(const bf16x8*)(bp + 32*512 + k0);
    bf16x8 b3 = *(const bf16x8*)(bp + 48*512 + k0);
    acc0 = __builtin_amdgcn_mfma_f32_16x16x32_bf16(a, b0, acc0, 0, 0, 0);
    acc1 = __builtin_amdgcn_mfma_f32_16x16x32_bf16(a, b1, acc1, 0, 0, 0);
    acc2 = __builtin_amdgcn_mfma_f32_16x16x32_bf16(a, b2, acc2, 0, 0, 0);
    acc3 = __builtin_amdgcn_mfma_f32_16x16x32_bf16(a, b3, acc3, 0, 0, 0);
  }

  const float* gm = (z == 0) ? gq : (z == 1) ? gk : nullptr;
  if (gm != nullptr) {
    const float g0 = gm[n0 +  0 + lr], g1 = gm[n0 + 16 + lr];
    const float g2 = gm[n0 + 32 + lr], g3 = gm[n0 + 48 + lr];
    #pragma unroll
    for (int r = 0; r < 4; ++r) {
      float ss = acc0[r]*acc0[r] + acc1[r]*acc1[r]
               + acc2[r]*acc2[r] + acc3[r]*acc3[r];
      ss += __shfl_xor(ss, 1, 64); ss += __shfl_xor(ss, 2, 64);
      ss += __shfl_xor(ss, 4, 64); ss += __shfl_xor(ss, 8, 64);
      float inv = 1.f / fmaxf(sqrtf(ss) * 0.125f, 1e-8f);  // ||x||*64^-0.5
      acc0[r] *= inv * g0; acc1[r] *= inv * g1;
      acc2[r] *= inv * g2; acc3[r] *= inv * g3;
    }
  }
  const int rbase = m0 + (l >> 4) * 4;
  #pragma unroll
  for (int r = 0; r < 4; ++r) {
    C[(long)(rbase + r)*512 + n0 +  0 + lr] = acc0[r];
    C[(long)(rbase + r)*512 + n0 + 16 + lr] = acc1[r];
    C[(long)(rbase + r)*512 + n0 + 32 + lr] = acc2[r];
    C[(long)(rbase + r)*512 + n0 + 48 + lr] = acc3[r];
  }
}

// ---------------------------------------------------------------------------
// K5a: per-chunk local prefixes. Block (c,h), 256 threads, NO LDS / NO SYNC.
// (unchanged from R3 — see comments there)
// ---------------------------------------------------------------------------
__global__ __launch_bounds__(256, 1) void k_chunk(
    const float* __restrict__ Qn, const float* __restrict__ Kn,
    const float* __restrict__ V,
    const float* __restrict__ wgt, const float* __restrict__ dec,
    float* __restrict__ Abar, float* __restrict__ Cbar,
    float* __restrict__ zbuf, float* __restrict__ cbuf)
{
  const int c = blockIdx.x, h = blockIdx.y;
  const int tid = threadIdx.x;
  const int row = tid >> 2, g = tid & 3, c0 = g * 16;

  float M[16], Nn[16], kk[8][16], vw[8], ww[8];
  #pragma unroll
  for (int j = 0; j < 16; ++j) {
    M[j] = (row == c0 + j) ? 1.f : 0.f;
    Nn[j] = 0.f;
  }
  #pragma unroll
  for (int j = 0; j < 16; ++j) kk[0][j] = 0.f;
  vw[0] = 0.f; ww[0] = 0.f;
  #pragma unroll
  for (int i = 0; i < 7; ++i) {
    const int t = c * CL - 7 + i;
    const int slot = i + 1;
    if (t >= 0) {
      const float4* kr = (const float4*)(Kn + (long)t*Dn + h*DHn + c0);
      #pragma unroll
      for (int j4 = 0; j4 < 4; ++j4) *(float4*)&kk[slot][j4*4] = kr[j4];
      vw[slot] = V[(long)t*Dn + h*DHn + row];
      ww[slot] = wgt[h*Tn + t];
    } else {
      #pragma unroll
      for (int j = 0; j < 16; ++j) kk[slot][j] = 0.f;
      vw[slot] = 0.f; ww[slot] = 0.f;
    }
  }

  for (int tb = 0; tb < 2; ++tb) {
    #pragma unroll
    for (int ii = 0; ii < 8; ++ii) {
      const int t = c * CL + tb * 8 + ii;
      {
        const float4* kr = (const float4*)(Kn + (long)t*Dn + h*DHn + c0);
        #pragma unroll
        for (int j4 = 0; j4 < 4; ++j4) *(float4*)&kk[ii][j4*4] = kr[j4];
      }
      vw[ii] = V[(long)t*Dn + h*DHn + row];
      ww[ii] = wgt[h*Tn + t];
      const float dc = dec[h*Tn + t];

      float uM[8], uN[8];
      #pragma unroll
      for (int s = 0; s < 8; ++s) {
        float a = 0.f, b = 0.f;
        #pragma unroll
        for (int j = 0; j < 16; ++j) {
          a = fmaf(M[j], kk[s][j], a);
          b = fmaf(Nn[j], kk[s][j], b);
        }
        a += __shfl_xor(a, 1, 64); a += __shfl_xor(a, 2, 64);
        b += __shfl_xor(b, 1, 64); b += __shfl_xor(b, 2, 64);
        uM[s] = a; uN[s] = b;
      }
      #pragma unroll
      for (int j = 0; j < 16; ++j) { M[j] *= dc; Nn[j] *= dc; }
      #pragma unroll
      for (int s = 0; s < 8; ++s) {
        const float cM = -dc * ww[s] * uM[s];
        const float cN = ww[s] * (vw[s] - dc * uN[s]);
        #pragma unroll
        for (int j = 0; j < 16; ++j) {
          M[j]  = fmaf(cM, kk[s][j], M[j]);
          Nn[j] = fmaf(cN, kk[s][j], Nn[j]);
        }
      }
      {
        float qv[16];
        const float4* qr = (const float4*)(Qn + (long)t*Dn + h*DHn + c0);
        #pragma unroll
        for (int j4 = 0; j4 < 4; ++j4) *(float4*)&qv[j4*4] = qr[j4];
        float zp = 0.f, cp = 0.f;
        #pragma unroll
        for (int j = 0; j < 16; ++j) {
          zp = fmaf(M[j], qv[j], zp);
          cp = fmaf(Nn[j], qv[j], cp);
        }
        zp += __shfl_xor(zp, 1, 64); zp += __shfl_xor(zp, 2, 64);
        cp += __shfl_xor(cp, 1, 64); cp += __shfl_xor(cp, 2, 64);
        if (g == 0) {
          zbuf[((long)h*Tn + t)*DHn + row] = zp;
          cbuf[((long)h*Tn + t)*DHn + row] = cp;
        }
      }
    }
  }
  float* Ao = Abar + (((long)(c*NH + h)) * 64 + row) * 64 + c0;
  float* Co = Cbar + (((long)(c*NH + h)) * 64 + row) * 64 + c0;
  #pragma unroll
  for (int j4 = 0; j4 < 4; ++j4) {
    *(float4*)&Ao[j4*4] = *(float4*)&M[j4*4];
    *(float4*)&Co[j4*4] = *(float4*)&Nn[j4*4];
  }
}

// ---------------------------------------------------------------------------
// K5b: state-only chunk scan with register double-buffer prefetch.
// ---------------------------------------------------------------------------
__global__ __launch_bounds__(64, 1) void k_scan(
    const float* __restrict__ Abar, const float* __restrict__ Cbar,
    const float* __restrict__ S0, float* __restrict__ Sst)
{
  const int h = blockIdx.x >> 6, m = blockIdx.x & 63, d = threadIdx.x;
  float s = S0[((long)h*DHn + m)*DHn + d];
  float a0[64], a1[64];
  float cb0, cb1;

#define PREF_(AR, CB, CI) do { \
    const float* Ac_ = Abar + ((long)(CI)*NH + h) * 4096; \
    _Pragma("unroll") \
    for (int l = 0; l < 64; ++l) AR[l] = Ac_[l*64 + d]; \
    CB = Cbar[((long)(CI)*NH + h) * 4096 + m*64 + d]; \
  } while (0)

#define STEP_(AR, CB) do { \
    float n0 = 0.f, n1 = 0.f, n2 = 0.f, n3 = 0.f; \
    _Pragma("unroll") \
    for (int l = 0; l < 16; ++l) { \
      n0 = fmaf(rdlane(s, l),      AR[l],      n0); \
      n1 = fmaf(rdlane(s, 16 + l), AR[16 + l], n1); \
      n2 = fmaf(rdlane(s, 32 + l), AR[32 + l], n2); \
      n3 = fmaf(rdlane(s, 48 + l), AR[48 + l], n3); \
    } \
    s = ((n0 + n1) + (n2 + n3)) + CB; \
  } while (0)

  PREF_(a0, cb0, 0);
  #pragma unroll 1
  for (int c = 0; c < NC; c += 2) {
    PREF_(a1, cb1, c + 1);
    Sst[(((long)c*NH + h)*64 + m)*64 + d] = s;
    STEP_(a0, cb0);
    const int cn = (c + 2 < NC) ? (c + 2) : (NC - 1);
    PREF_(a0, cb0, cn);
    Sst[(((long)(c+1)*NH + h)*64 + m)*64 + d] = s;
    STEP_(a1, cb1);
  }
#undef PREF_
#undef STEP_
}

// ---------------------------------------------------------------------------
// K5c: parallel output eval -> bf16 Y (operand of the Wo GEMM).
// ---------------------------------------------------------------------------
__global__ __launch_bounds__(256, 1) void k_yout(
    const float* __restrict__ Sst, const float* __restrict__ zbuf,
    const float* __restrict__ cbuf, ushort* __restrict__ Y)
{
  const int c = blockIdx.x, h = blockIdx.y;
  const int tid = threadIdx.x, m = tid & 63, tg = tid >> 6;
  __shared__ float Zl[CL][DHn];
  {
    const float4* Zc = (const float4*)(zbuf + ((long)h*Tn + c*CL) * DHn);
    ((float4*)&Zl[0][0])[tid] = Zc[tid];
  }
  const float* Srow = Sst + (((long)c*NH + h)*64 + m) * 64;
  float sr[64];
  #pragma unroll
  for (int q4 = 0; q4 < 16; ++q4)
    *(float4*)&sr[q4*4] = ((const float4*)Srow)[q4];
  __syncthreads();
  const float* Cc = cbuf + ((long)h*Tn + c*CL) * DHn;
  #pragma unroll
  for (int it = 0; it < 4; ++it) {
    const int tt = tg*4 + it;
    float y = 0.f;
    #pragma unroll
    for (int l = 0; l < 64; ++l) y = fmaf(sr[l], Zl[tt][l], y);
    Y[((long)(c*CL + tt))*Dn + h*DHn + m] = f2bf(y + Cc[tt*DHn + m]);
  }
}

// ---------------------------------------------------------------------------
extern "C" void kernel_launch(void* const* d_in, const int* in_sizes, int n_in,
                              void* d_out, int out_size, void* d_ws, size_t ws_size,
                              hipStream_t stream)
{
  const float* x   = (const float*)d_in[0];
  const float* pw  = (const float*)d_in[1];
  const float* Wq  = (const float*)d_in[2];
  const float* Wk  = (const float*)d_in[3];
  const float* Wv  = (const float*)d_in[4];
  const float* Wo  = (const float*)d_in[5];
  const float* qcw = (const float*)d_in[6];
  const float* kcw = (const float*)d_in[7];
  const float* vcw = (const float*)d_in[8];
  const float* lrw = (const float*)d_in[9];
  const float* lrb = (const float*)d_in[10];
  const float* dw  = (const float*)d_in[11];
  const float* db  = (const float*)d_in[12];
  const float* gw  = (const float*)d_in[13];
  const float* gb  = (const float*)d_in[14];
  const float* qg  = (const float*)d_in[15];
  const float* kg  = (const float*)d_in[16];
  const float* S0  = (const float*)d_in[17];
  float* out = (float*)d_out;
  float* ws  = (float*)d_ws;

  const long N = (long)Tn * Dn;   // 262144 floats per 512x512 fp32 matrix
  // Layout (float units; overlays are ordered-safe under stream serialization):
  //  [0,1N):    xn (dead after k_conv)        \
  //  [1,2.5N):  qkv bf16 (dead after QKV GEMM) > overlaid by Abar [0,4N)
  //  [4,8N):    Cbar
  //  [8,11N):   Qb/Kb/Vb fp32 (dead after k_chunk) -> Sst [8,12N)
  //  [12,13N):  zbuf   [13,14N): cbuf
  //  [14,16N):  Wbf (4 matrices bf16, live to the end)
  //  [16,16.5N): Ybf bf16
  //  [16.5N+):  wgt, dcb
  float*  xn    = ws;
  ushort* qkvbf = (ushort*)(ws + 1*N);
  float*  Abar  = ws;
  float*  Cbar  = ws + 4*N;
  float*  Qb    = ws + 8*N;
  float*  Sst   = ws + 8*N;
  float*  zbuf  = ws + 12*N;
  float*  cbuf  = ws + 13*N;
  ushort* Wbf   = (ushort*)(ws + 14*N);
  ushort* Ybf   = (ushort*)(ws + 16*N);
  float*  wgt   = ws + 16*N + N/2;    // [NH][T]
  float*  dcb   = wgt + NH*Tn;        // [NH][T]

  k_norm_gates<<<Tn, 256, 0, stream>>>(x, pw, lrw, lrb, dw, db, gw, gb,
                                       xn, wgt, dcb);
  k_cvt_w<<<dim3(256, 4), 256, 0, stream>>>(Wq, Wk, Wv, Wo, Wbf);
  k_conv<<<Tn, Dn, 0, stream>>>(xn, qcw, kcw, vcw,
                                qkvbf, qkvbf + NW, qkvbf + 2*NW);
  k_gemm_bf<<<dim3(16, 8, 3), 128, 0, stream>>>(qkvbf, NW, Wbf, NW,
                                                Qb, N, qg, kg);
  k_chunk<<<dim3(NC, NH), 256, 0, stream>>>(Qb, Qb + N, Qb + 2*N, wgt, dcb,
                                            Abar, Cbar, zbuf, cbuf);
  k_scan<<<NH * DHn, 64, 0, stream>>>(Abar, Cbar, S0, Sst);
  k_yout<<<dim3(NC, NH), 256, 0, stream>>>(Sst, zbuf, cbuf, Ybf);
  k_gemm_bf<<<dim3(16, 8, 1), 128, 0, stream>>>(Ybf, 0, Wbf + 3*NW, 0,
                                                out, 0, nullptr, nullptr);
}